// Round 4
// baseline (215.082 us; speedup 1.0000x reference)
//
#include <hip/hip_runtime.h>

#define NNODE  50000
#define NHEDGE 10000
#define NEDGE  300000
#define HD     256
#define NS     (NHEDGE + NNODE)   // 60000 combined segments
#define SCAN_B 59                 // ceil(NS/1024)

typedef __attribute__((ext_vector_type(8))) short bf16x8;
typedef __attribute__((ext_vector_type(8))) unsigned short u16x8;
typedef __attribute__((ext_vector_type(4))) float f32x4;

__device__ __forceinline__ float prelu(float v, float a){ return v > 0.f ? v : a*v; }
__device__ __forceinline__ unsigned short f2bf(float f){
  unsigned u = __float_as_uint(f);
  return (unsigned short)((u + 0x7FFFu + ((u>>16)&1u)) >> 16);   // RNE
}
__device__ __forceinline__ float bf2f(unsigned short h){
  return __uint_as_float(((unsigned)h) << 16);
}

// ---------------------------------------------------------------------------
// Weight prep, one block per output row o:
//   Wb0[o][i] = bf16( sum_h W_n2e[o][h]*W_in[h][i] )   (B for GEMM0, [n][k])
//   Wb1[o][i] = bf16( W_e2n[o][i] )                    (B for GEMM1, [n][k])
//   bc[o]     = dot(W_n2e[o,:], b_in) + b_n2e[o]       (LDS reduce, no straggler)
// ---------------------------------------------------------------------------
__global__ __launch_bounds__(256) void k_wprep(
    const float* __restrict__ W_in, const float* __restrict__ b_in,
    const float* __restrict__ W_n2e, const float* __restrict__ b_n2e,
    const float* __restrict__ W_e2n,
    unsigned short* __restrict__ Wb0, unsigned short* __restrict__ Wb1,
    float* __restrict__ bc){
  int o = blockIdx.x, t = threadIdx.x;
  __shared__ float wn[HD];
  __shared__ float red[4];
  wn[t] = W_n2e[(size_t)o*HD + t];
  __syncthreads();
  // bias fold: bc[o] = sum_t wn[t]*b_in[t]  (wave shuffle + LDS)
  float pb = wn[t] * b_in[t];
  #pragma unroll
  for(int d = 32; d > 0; d >>= 1) pb += __shfl_down(pb, d);
  if((t & 63) == 0) red[t >> 6] = pb;
  // weight fold (coalesced W_in rows, L2-resident after first block)
  float acc = 0.f;
  #pragma unroll 8
  for(int h = 0; h < HD; ++h) acc += wn[h] * W_in[(size_t)h*HD + t];
  Wb0[(size_t)o*HD + t] = f2bf(acc);
  Wb1[(size_t)o*HD + t] = f2bf(W_e2n[(size_t)o*HD + t]);
  __syncthreads();
  if(t == 0) bc[o] = red[0] + red[1] + red[2] + red[3] + b_n2e[o];
}

// ---------------------------------------------------------------------------
// n_feat f32 -> bf16 table (pure streaming; one thread = 8 elems)
// ---------------------------------------------------------------------------
__global__ __launch_bounds__(256) void k_cvt(const float* __restrict__ n_feat,
                                             unsigned short* __restrict__ nf_b){
  size_t i8 = (size_t)blockIdx.x*256 + threadIdx.x;
  const float4* f4 = (const float4*)n_feat;
  float4 a = f4[i8*2], c = f4[i8*2 + 1];
  u16x8 o;
  o[0] = f2bf(a.x); o[1] = f2bf(a.y); o[2] = f2bf(a.z); o[3] = f2bf(a.w);
  o[4] = f2bf(c.x); o[5] = f2bf(c.y); o[6] = f2bf(c.z); o[7] = f2bf(c.w);
  ((u16x8*)nf_b)[i8] = o;
}

// ---------------------------------------------------------------------------
// Combined histogram: cnts[0..NHEDGE) hedge sizes, cnts[NHEDGE..NS) node sizes
// ---------------------------------------------------------------------------
__global__ void k_hist(const int* __restrict__ node_idx, const int* __restrict__ hedge_idx,
                       int* __restrict__ cnts){
  int e = blockIdx.x*256 + threadIdx.x;
  if(e < NEDGE){
    atomicAdd(&cnts[hedge_idx[e]], 1);
    atomicAdd(&cnts[NHEDGE + node_idx[e]], 1);
  }
}

// ---------------------------------------------------------------------------
// Parallel exclusive scan over NS counts: A) block sums  B) scan partials  C) emit
// ---------------------------------------------------------------------------
__global__ __launch_bounds__(256) void k_scanA(const int* __restrict__ cnts, int* __restrict__ bsum){
  int idx4 = blockIdx.x*256 + threadIdx.x;
  int4 v = make_int4(0,0,0,0);
  if(idx4 < NS/4) v = ((const int4*)cnts)[idx4];
  int s = v.x + v.y + v.z + v.w;
  __shared__ int red[256];
  red[threadIdx.x] = s; __syncthreads();
  for(int d = 128; d > 0; d >>= 1){
    if(threadIdx.x < d) red[threadIdx.x] += red[threadIdx.x + d];
    __syncthreads();
  }
  if(threadIdx.x == 0) bsum[blockIdx.x] = red[0];
}

__global__ __launch_bounds__(64) void k_scanB(int* __restrict__ bsum){
  __shared__ int sb[SCAN_B];
  int t = threadIdx.x;
  if(t < SCAN_B) sb[t] = bsum[t];
  __syncthreads();
  if(t == 0){ int run = 0; for(int i = 0; i < SCAN_B; ++i){ int v = sb[i]; sb[i] = run; run += v; } }
  __syncthreads();
  if(t < SCAN_B) bsum[t] = sb[t];
}

__global__ __launch_bounds__(256) void k_scanC(const int* __restrict__ cnts, const int* __restrict__ bsum,
                                               int* __restrict__ offs, int* __restrict__ pos){
  int t = threadIdx.x;
  int idx4 = blockIdx.x*256 + t;
  int4 v = make_int4(0,0,0,0);
  if(idx4 < NS/4){
    v = ((const int4*)cnts)[idx4];
    ((int4*)pos)[idx4] = make_int4(0,0,0,0);   // zero pos for k_fill
  }
  int s = v.x + v.y + v.z + v.w;
  __shared__ int sc[256];
  sc[t] = s; __syncthreads();
  for(int d = 1; d < 256; d <<= 1){
    int q = (t >= d) ? sc[t-d] : 0; __syncthreads();
    sc[t] += q; __syncthreads();
  }
  int excl = sc[t] - s + bsum[blockIdx.x];
  int base = idx4*4;
  if(base < NS){
    int r = excl;
    offs[base]   = r; r += v.x;
    offs[base+1] = r; r += v.y;
    offs[base+2] = r; r += v.z;
    offs[base+3] = r;
  }
  if(blockIdx.x == SCAN_B-1 && t == 255) offs[NS] = sc[255] + bsum[blockIdx.x];
}

// ---------------------------------------------------------------------------
// Fill CSR buckets (hedge buckets in csrc[0..NEDGE), node buckets after).
// ---------------------------------------------------------------------------
__global__ void k_fill(const int* __restrict__ node_idx, const int* __restrict__ hedge_idx,
                       const int* __restrict__ offs, int* __restrict__ pos,
                       int* __restrict__ csrc){
  int e = blockIdx.x*256 + threadIdx.x;
  if(e < NEDGE){
    int j = hedge_idx[e];
    int n = node_idx[e];
    int p = offs[j] + atomicAdd(&pos[j], 1);
    csrc[p] = n;
    int q = offs[NHEDGE + n] + atomicAdd(&pos[NHEDGE + n], 1);
    csrc[q] = j;
  }
}

// ---------------------------------------------------------------------------
// Phase-1 aggregation from bf16 table -> bf16 aggx + f32 aggw.
// One wave per hedge, lane = 4 cols (ushort4 = 8B). Depth-2 prefetch.
// ---------------------------------------------------------------------------
__global__ __launch_bounds__(256) void k_agg1(const unsigned short* __restrict__ nf_b,
        const float* __restrict__ nrw,
        const int* __restrict__ offs, const int* __restrict__ csrc,
        unsigned short* __restrict__ aggx_b, float* __restrict__ aggw){
  int wv = threadIdx.x >> 6, lane = threadIdx.x & 63;
  int j = blockIdx.x*4 + wv;
  int b = offs[j], cnt = offs[j+1] - b;
  const ushort4* tab = (const ushort4*)nf_b;
  float4 acc = make_float4(0.f,0.f,0.f,0.f);
  float sw = 0.f;
  ushort4 vA = {0,0,0,0}, vB = {0,0,0,0};
  float wA = 0.f, wB = 0.f;
  if(cnt > 0){ int n = csrc[b];   wA = nrw[n]; vA = tab[(size_t)n*64 + lane]; }
  if(cnt > 1){ int n = csrc[b+1]; wB = nrw[n]; vB = tab[(size_t)n*64 + lane]; }
  int k = 0;
  while(k < cnt){
    {
      ushort4 cv = vA; float cw = wA;
      if(k + 2 < cnt){ int n = csrc[b+k+2]; wA = nrw[n]; vA = tab[(size_t)n*64 + lane]; }
      acc.x += cw*bf2f(cv.x); acc.y += cw*bf2f(cv.y);
      acc.z += cw*bf2f(cv.z); acc.w += cw*bf2f(cv.w);
      sw += cw;
    }
    if(++k >= cnt) break;
    {
      ushort4 cv = vB; float cw = wB;
      if(k + 2 < cnt){ int n = csrc[b+k+2]; wB = nrw[n]; vB = tab[(size_t)n*64 + lane]; }
      acc.x += cw*bf2f(cv.x); acc.y += cw*bf2f(cv.y);
      acc.z += cw*bf2f(cv.z); acc.w += cw*bf2f(cv.w);
      sw += cw;
    }
    ++k;
  }
  ushort4 ob;
  ob.x = f2bf(acc.x); ob.y = f2bf(acc.y); ob.z = f2bf(acc.z); ob.w = f2bf(acc.w);
  *(ushort4*)&aggx_b[(size_t)j*HD + lane*4] = ob;
  if(lane == 0) aggw[j] = sw;
}

// ---------------------------------------------------------------------------
// MFMA bf16 GEMM: per wave a 32x64 output tile, operands straight from L2.
// MODE 0: v = prelu((dot + rs_a[r]*cb[c]) / rs_b[r]) -> out_f (f32) + out_b (bf16)
// MODE 1: v = rs_a[r] * (dot + cb[c])               -> out_b (bf16)
// ---------------------------------------------------------------------------
template<int MODE>
__global__ __launch_bounds__(256) void k_gemm(const unsigned short* __restrict__ xb,
        const unsigned short* __restrict__ Wb,
        const float* __restrict__ rs_a, const float* __restrict__ rs_b,
        const float* __restrict__ cb, const float* __restrict__ alpha_p,
        float* __restrict__ out_f, unsigned short* __restrict__ out_b, int M){
  int wv = threadIdx.x >> 6, lane = threadIdx.x & 63;
  int m0 = blockIdx.x*128 + wv*32;
  int n0 = blockIdx.y*64;
  if(m0 >= M) return;
  int lr = lane & 15;
  int lk = (lane >> 4) << 3;
  f32x4 acc[2][4];
  #pragma unroll
  for(int a = 0; a < 2; ++a)
    #pragma unroll
    for(int b = 0; b < 4; ++b) acc[a][b] = (f32x4){0.f,0.f,0.f,0.f};
  const bf16x8 zero8 = {0,0,0,0,0,0,0,0};
  #pragma unroll
  for(int kc = 0; kc < HD; kc += 32){
    bf16x8 af[2], bf[4];
    #pragma unroll
    for(int mi = 0; mi < 2; ++mi){
      int r = m0 + mi*16 + lr;
      af[mi] = (r < M) ? *(const bf16x8*)&xb[(size_t)r*HD + kc + lk] : zero8;
    }
    #pragma unroll
    for(int ni = 0; ni < 4; ++ni){
      int c = n0 + ni*16 + lr;
      bf[ni] = *(const bf16x8*)&Wb[(size_t)c*HD + kc + lk];
    }
    #pragma unroll
    for(int mi = 0; mi < 2; ++mi)
      #pragma unroll
      for(int ni = 0; ni < 4; ++ni)
        acc[mi][ni] = __builtin_amdgcn_mfma_f32_16x16x32_bf16(af[mi], bf[ni], acc[mi][ni], 0, 0, 0);
  }
  float alpha = (MODE == 0) ? *alpha_p : 0.f;
  int rb = (lane >> 4) << 2;
  #pragma unroll
  for(int mi = 0; mi < 2; ++mi){
    #pragma unroll
    for(int j = 0; j < 4; ++j){
      int r = m0 + mi*16 + rb + j;
      if(r < M){
        float ra = rs_a[r];
        float inv = (MODE == 0) ? 1.f / rs_b[r] : 0.f;
        #pragma unroll
        for(int ni = 0; ni < 4; ++ni){
          int c = n0 + ni*16 + lr;
          float d = acc[mi][ni][j];
          if(MODE == 0){
            float v = (d + ra*cb[c]) * inv;
            v = prelu(v, alpha);
            out_f[(size_t)r*HD + c] = v;
            out_b[(size_t)r*HD + c] = f2bf(v);
          } else {
            float v = ra * (d + cb[c]);
            out_b[(size_t)r*HD + c] = f2bf(v);
          }
        }
      }
    }
  }
}

// ---------------------------------------------------------------------------
// Phase-2 aggregation from bf16 y + final epilogue. Depth-2 prefetch.
// ---------------------------------------------------------------------------
__global__ __launch_bounds__(256) void k_agg2(const unsigned short* __restrict__ yb,
        const int* __restrict__ offs, const int* __restrict__ csrc,
        const float* __restrict__ nrs, const float* __restrict__ alpha_p,
        float* __restrict__ out_nodes){
  int wv = threadIdx.x >> 6, lane = threadIdx.x & 63;
  int i = blockIdx.x*4 + wv;
  int b = offs[NHEDGE + i], cnt = offs[NHEDGE + i + 1] - b;
  const ushort4* tab = (const ushort4*)yb;
  float4 acc = make_float4(0.f,0.f,0.f,0.f);
  ushort4 vA = {0,0,0,0}, vB = {0,0,0,0};
  if(cnt > 0){ int j = csrc[b];   vA = tab[(size_t)j*64 + lane]; }
  if(cnt > 1){ int j = csrc[b+1]; vB = tab[(size_t)j*64 + lane]; }
  int k = 0;
  while(k < cnt){
    {
      ushort4 cv = vA;
      if(k + 2 < cnt){ int j = csrc[b+k+2]; vA = tab[(size_t)j*64 + lane]; }
      acc.x += bf2f(cv.x); acc.y += bf2f(cv.y); acc.z += bf2f(cv.z); acc.w += bf2f(cv.w);
    }
    if(++k >= cnt) break;
    {
      ushort4 cv = vB;
      if(k + 2 < cnt){ int j = csrc[b+k+2]; vB = tab[(size_t)j*64 + lane]; }
      acc.x += bf2f(cv.x); acc.y += bf2f(cv.y); acc.z += bf2f(cv.z); acc.w += bf2f(cv.w);
    }
    ++k;
  }
  float inv = 1.f / nrs[i];
  float a = *alpha_p;
  float4 o;
  o.x = prelu(acc.x*inv, a); o.y = prelu(acc.y*inv, a);
  o.z = prelu(acc.z*inv, a); o.w = prelu(acc.w*inv, a);
  *(float4*)&out_nodes[(size_t)i*HD + lane*4] = o;
}

// ---------------------------------------------------------------------------
extern "C" void kernel_launch(void* const* d_in, const int* in_sizes, int n_in,
                              void* d_out, int out_size, void* d_ws, size_t ws_size,
                              hipStream_t stream){
  const float* n_feat   = (const float*)d_in[0];
  const int*   node_idx  = (const int*)d_in[2];
  const int*   hedge_idx = (const int*)d_in[3];
  const float* nrw  = (const float*)d_in[4];
  const float* nrs  = (const float*)d_in[5];
  const float* hrw  = (const float*)d_in[6];
  const float* hrs  = (const float*)d_in[7];
  const float* W_in  = (const float*)d_in[8];
  const float* b_in  = (const float*)d_in[9];
  const float* W_n2e = (const float*)d_in[10];
  const float* b_n2e = (const float*)d_in[11];
  const float* W_e2n = (const float*)d_in[12];
  const float* b_e2n = (const float*)d_in[13];
  const float* alpha = (const float*)d_in[14];

  float* out_nodes = (float*)d_out;
  float* out_efeat = out_nodes + (size_t)NNODE * HD;

  // bf16 n_feat table lives in the out_nodes region of d_out: it is consumed
  // only by k_agg1, and k_agg2 (the last kernel) fully overwrites out_nodes.
  unsigned short* nf_b = (unsigned short*)out_nodes;

  char* p = (char*)d_ws;
  auto take = [&](size_t bytes) -> void* {
    void* r = (void*)p;
    p += (bytes + 255) & ~(size_t)255;
    return r;
  };
  unsigned short* Wb0     = (unsigned short*)take((size_t)HD*HD*2);
  unsigned short* Wb1     = (unsigned short*)take((size_t)HD*HD*2);
  float*          bc      = (float*)take(HD*4);
  float*          aggw    = (float*)take(NHEDGE*4);
  unsigned short* aggx_b  = (unsigned short*)take((size_t)NHEDGE*HD*2);  // aliased as ybuf_b
  unsigned short* efeat_b = (unsigned short*)take((size_t)NHEDGE*HD*2);
  int*            offs    = (int*)take((NS+1)*4);
  int*            cnts    = (int*)take((size_t)NS*4);
  int*            pos     = (int*)take((size_t)NS*4);
  int*            bsum    = (int*)take(SCAN_B*4);
  int*            csrc    = (int*)take((size_t)2*NEDGE*4);
  unsigned short* ybuf_b  = aggx_b;  // safe alias: aggx dead after k_gemm<0>

  hipMemsetAsync(cnts, 0, (size_t)NS*4, stream);

  k_wprep<<<HD, 256, 0, stream>>>(W_in, b_in, W_n2e, b_n2e, W_e2n, Wb0, Wb1, bc);
  k_cvt<<<(NNODE*HD)/(256*8), 256, 0, stream>>>(n_feat, nf_b);
  k_hist<<<(NEDGE+255)/256, 256, 0, stream>>>(node_idx, hedge_idx, cnts);
  k_scanA<<<SCAN_B, 256, 0, stream>>>(cnts, bsum);
  k_scanB<<<1, 64, 0, stream>>>(bsum);
  k_scanC<<<SCAN_B, 256, 0, stream>>>(cnts, bsum, offs, pos);
  k_fill<<<(NEDGE+255)/256, 256, 0, stream>>>(node_idx, hedge_idx, offs, pos, csrc);
  k_agg1<<<NHEDGE/4, 256, 0, stream>>>(nf_b, nrw, offs, csrc, aggx_b, aggw);
  k_gemm<0><<<dim3((NHEDGE+127)/128, 4), 256, 0, stream>>>(aggx_b, Wb0, aggw, hrs, bc, alpha,
                                                           out_efeat, efeat_b, NHEDGE);
  k_gemm<1><<<dim3((NHEDGE+127)/128, 4), 256, 0, stream>>>(efeat_b, Wb1, hrw, nullptr, b_e2n, alpha,
                                                           nullptr, ybuf_b, NHEDGE);
  k_agg2<<<NNODE/4, 256, 0, stream>>>(ybuf_b, offs, csrc, nrs, alpha, out_nodes);
}

// Round 5
// 207.410 us; speedup vs baseline: 1.0370x; 1.0370x over previous
//
#include <hip/hip_runtime.h>

#define NNODE  50000
#define NHEDGE 10000
#define NEDGE  300000
#define HD     256
#define NS     (NHEDGE + NNODE)   // 60000 combined segments
#define SCAN_B 59                 // ceil(NS/1024)

typedef __attribute__((ext_vector_type(8))) short bf16x8;
typedef __attribute__((ext_vector_type(8))) unsigned short u16x8;
typedef __attribute__((ext_vector_type(4))) float f32x4;

__device__ __forceinline__ float prelu(float v, float a){ return v > 0.f ? v : a*v; }
__device__ __forceinline__ unsigned short f2bf(float f){
  unsigned u = __float_as_uint(f);
  return (unsigned short)((u + 0x7FFFu + ((u>>16)&1u)) >> 16);   // RNE
}
__device__ __forceinline__ float bf2f(unsigned short h){
  return __uint_as_float(((unsigned)h) << 16);
}

// ---------------------------------------------------------------------------
// Weight prep, one block per output row o:
//   Wb0[o][i] = bf16( sum_h W_n2e[o][h]*W_in[h][i] )   (B for GEMM0, [n][k])
//   Wb1[o][i] = bf16( W_e2n[o][i] )                    (B for GEMM1, [n][k])
//   bc[o]     = dot(W_n2e[o,:], b_in) + b_n2e[o]       (LDS reduce)
//   also zeroes cnts[] (replaces the 43 µs runtime fillBuffer dispatch)
// ---------------------------------------------------------------------------
__global__ __launch_bounds__(256) void k_wprep(
    const float* __restrict__ W_in, const float* __restrict__ b_in,
    const float* __restrict__ W_n2e, const float* __restrict__ b_n2e,
    const float* __restrict__ W_e2n,
    unsigned short* __restrict__ Wb0, unsigned short* __restrict__ Wb1,
    float* __restrict__ bc, int* __restrict__ cnts){
  int o = blockIdx.x, t = threadIdx.x;
  int zi = o*256 + t;
  if(zi < NS) cnts[zi] = 0;          // zero histogram (65536 threads >= NS)
  __shared__ float wn[HD];
  __shared__ float red[4];
  wn[t] = W_n2e[(size_t)o*HD + t];
  __syncthreads();
  float pb = wn[t] * b_in[t];
  #pragma unroll
  for(int d = 32; d > 0; d >>= 1) pb += __shfl_down(pb, d);
  if((t & 63) == 0) red[t >> 6] = pb;
  float acc = 0.f;
  #pragma unroll 8
  for(int h = 0; h < HD; ++h) acc += wn[h] * W_in[(size_t)h*HD + t];
  Wb0[(size_t)o*HD + t] = f2bf(acc);
  Wb1[(size_t)o*HD + t] = f2bf(W_e2n[(size_t)o*HD + t]);
  __syncthreads();
  if(t == 0) bc[o] = red[0] + red[1] + red[2] + red[3] + b_n2e[o];
}

// ---------------------------------------------------------------------------
// n_feat f32 -> bf16 table, PRE-SCALED by node_reg_weight:
//   tabw[n][c] = bf16( nrw[n] * n_feat[n][c] )     (one thread = 8 elems)
// ---------------------------------------------------------------------------
__global__ __launch_bounds__(256) void k_cvt(const float* __restrict__ n_feat,
                                             const float* __restrict__ nrw,
                                             unsigned short* __restrict__ tabw){
  size_t i8 = (size_t)blockIdx.x*256 + threadIdx.x;
  int row = (int)(i8 >> 5);            // 32 x u16x8 per 256-col row
  float w = nrw[row];
  const float4* f4 = (const float4*)n_feat;
  float4 a = f4[i8*2], c = f4[i8*2 + 1];
  u16x8 o;
  o[0] = f2bf(w*a.x); o[1] = f2bf(w*a.y); o[2] = f2bf(w*a.z); o[3] = f2bf(w*a.w);
  o[4] = f2bf(w*c.x); o[5] = f2bf(w*c.y); o[6] = f2bf(w*c.z); o[7] = f2bf(w*c.w);
  ((u16x8*)tabw)[i8] = o;
}

// ---------------------------------------------------------------------------
// Combined histogram: cnts[0..NHEDGE) hedge sizes, cnts[NHEDGE..NS) node sizes
// ---------------------------------------------------------------------------
__global__ void k_hist(const int* __restrict__ node_idx, const int* __restrict__ hedge_idx,
                       int* __restrict__ cnts){
  int e = blockIdx.x*256 + threadIdx.x;
  if(e < NEDGE){
    atomicAdd(&cnts[hedge_idx[e]], 1);
    atomicAdd(&cnts[NHEDGE + node_idx[e]], 1);
  }
}

// ---------------------------------------------------------------------------
// Parallel exclusive scan over NS counts: A) block sums  B) scan partials  C) emit
// ---------------------------------------------------------------------------
__global__ __launch_bounds__(256) void k_scanA(const int* __restrict__ cnts, int* __restrict__ bsum){
  int idx4 = blockIdx.x*256 + threadIdx.x;
  int4 v = make_int4(0,0,0,0);
  if(idx4 < NS/4) v = ((const int4*)cnts)[idx4];
  int s = v.x + v.y + v.z + v.w;
  __shared__ int red[256];
  red[threadIdx.x] = s; __syncthreads();
  for(int d = 128; d > 0; d >>= 1){
    if(threadIdx.x < d) red[threadIdx.x] += red[threadIdx.x + d];
    __syncthreads();
  }
  if(threadIdx.x == 0) bsum[blockIdx.x] = red[0];
}

__global__ __launch_bounds__(64) void k_scanB(int* __restrict__ bsum){
  __shared__ int sb[SCAN_B];
  int t = threadIdx.x;
  if(t < SCAN_B) sb[t] = bsum[t];
  __syncthreads();
  if(t == 0){ int run = 0; for(int i = 0; i < SCAN_B; ++i){ int v = sb[i]; sb[i] = run; run += v; } }
  __syncthreads();
  if(t < SCAN_B) bsum[t] = sb[t];
}

__global__ __launch_bounds__(256) void k_scanC(const int* __restrict__ cnts, const int* __restrict__ bsum,
                                               int* __restrict__ offs, int* __restrict__ pos){
  int t = threadIdx.x;
  int idx4 = blockIdx.x*256 + t;
  int4 v = make_int4(0,0,0,0);
  if(idx4 < NS/4){
    v = ((const int4*)cnts)[idx4];
    ((int4*)pos)[idx4] = make_int4(0,0,0,0);   // zero pos for k_fill
  }
  int s = v.x + v.y + v.z + v.w;
  __shared__ int sc[256];
  sc[t] = s; __syncthreads();
  for(int d = 1; d < 256; d <<= 1){
    int q = (t >= d) ? sc[t-d] : 0; __syncthreads();
    sc[t] += q; __syncthreads();
  }
  int excl = sc[t] - s + bsum[blockIdx.x];
  int base = idx4*4;
  if(base < NS){
    int r = excl;
    offs[base]   = r; r += v.x;
    offs[base+1] = r; r += v.y;
    offs[base+2] = r; r += v.z;
    offs[base+3] = r;
  }
  if(blockIdx.x == SCAN_B-1 && t == 255) offs[NS] = sc[255] + bsum[blockIdx.x];
}

// ---------------------------------------------------------------------------
// Fill CSR buckets (hedge buckets in csrc[0..NEDGE), node buckets after).
// ---------------------------------------------------------------------------
__global__ void k_fill(const int* __restrict__ node_idx, const int* __restrict__ hedge_idx,
                       const int* __restrict__ offs, int* __restrict__ pos,
                       int* __restrict__ csrc){
  int e = blockIdx.x*256 + threadIdx.x;
  if(e < NEDGE){
    int j = hedge_idx[e];
    int n = node_idx[e];
    int p = offs[j] + atomicAdd(&pos[j], 1);
    csrc[p] = n;
    int q = offs[NHEDGE + n] + atomicAdd(&pos[NHEDGE + n], 1);
    csrc[q] = j;
  }
}

// ---------------------------------------------------------------------------
// Phase-1 aggregation from pre-scaled bf16 table -> bf16 aggx + f32 aggw.
// One wave per hedge, lane = 4 cols (ushort4 = 8B). Depth-4 prefetch.
// ---------------------------------------------------------------------------
__global__ __launch_bounds__(256) void k_agg1(const unsigned short* __restrict__ tabw,
        const float* __restrict__ nrw,
        const int* __restrict__ offs, const int* __restrict__ csrc,
        unsigned short* __restrict__ aggx_b, float* __restrict__ aggw){
  int wv = threadIdx.x >> 6, lane = threadIdx.x & 63;
  int j = blockIdx.x*4 + wv;
  int b = offs[j], cnt = offs[j+1] - b;
  const ushort4* tab = (const ushort4*)tabw;
  float4 acc = make_float4(0.f,0.f,0.f,0.f);
  float sw = 0.f;
  ushort4 v0={0,0,0,0}, v1={0,0,0,0}, v2={0,0,0,0}, v3={0,0,0,0};
  float w0=0.f, w1=0.f, w2=0.f, w3=0.f;
  if(cnt > 0){ int n = csrc[b];   w0 = nrw[n]; v0 = tab[(size_t)n*64 + lane]; }
  if(cnt > 1){ int n = csrc[b+1]; w1 = nrw[n]; v1 = tab[(size_t)n*64 + lane]; }
  if(cnt > 2){ int n = csrc[b+2]; w2 = nrw[n]; v2 = tab[(size_t)n*64 + lane]; }
  if(cnt > 3){ int n = csrc[b+3]; w3 = nrw[n]; v3 = tab[(size_t)n*64 + lane]; }
  int k = 0;
  while(k < cnt){
    { ushort4 cv = v0; float cw = w0;
      if(k + 4 < cnt){ int n = csrc[b+k+4]; w0 = nrw[n]; v0 = tab[(size_t)n*64 + lane]; }
      acc.x += bf2f(cv.x); acc.y += bf2f(cv.y); acc.z += bf2f(cv.z); acc.w += bf2f(cv.w);
      sw += cw; }
    if(++k >= cnt) break;
    { ushort4 cv = v1; float cw = w1;
      if(k + 4 < cnt){ int n = csrc[b+k+4]; w1 = nrw[n]; v1 = tab[(size_t)n*64 + lane]; }
      acc.x += bf2f(cv.x); acc.y += bf2f(cv.y); acc.z += bf2f(cv.z); acc.w += bf2f(cv.w);
      sw += cw; }
    if(++k >= cnt) break;
    { ushort4 cv = v2; float cw = w2;
      if(k + 4 < cnt){ int n = csrc[b+k+4]; w2 = nrw[n]; v2 = tab[(size_t)n*64 + lane]; }
      acc.x += bf2f(cv.x); acc.y += bf2f(cv.y); acc.z += bf2f(cv.z); acc.w += bf2f(cv.w);
      sw += cw; }
    if(++k >= cnt) break;
    { ushort4 cv = v3; float cw = w3;
      if(k + 4 < cnt){ int n = csrc[b+k+4]; w3 = nrw[n]; v3 = tab[(size_t)n*64 + lane]; }
      acc.x += bf2f(cv.x); acc.y += bf2f(cv.y); acc.z += bf2f(cv.z); acc.w += bf2f(cv.w);
      sw += cw; }
    ++k;
  }
  ushort4 ob;
  ob.x = f2bf(acc.x); ob.y = f2bf(acc.y); ob.z = f2bf(acc.z); ob.w = f2bf(acc.w);
  *(ushort4*)&aggx_b[(size_t)j*HD + lane*4] = ob;
  if(lane == 0) aggw[j] = sw;
}

// ---------------------------------------------------------------------------
// MFMA bf16 GEMM: per wave a 32x64 output tile, operands straight from L2.
// MODE 0: v = prelu((dot + rs_a[r]*cb[c]) / rs_b[r]) -> out_f (f32) + out_b (bf16)
// MODE 1: v = rs_a[r] * (dot + cb[c])               -> out_b (bf16)
// ---------------------------------------------------------------------------
template<int MODE>
__global__ __launch_bounds__(256) void k_gemm(const unsigned short* __restrict__ xb,
        const unsigned short* __restrict__ Wb,
        const float* __restrict__ rs_a, const float* __restrict__ rs_b,
        const float* __restrict__ cb, const float* __restrict__ alpha_p,
        float* __restrict__ out_f, unsigned short* __restrict__ out_b, int M){
  int wv = threadIdx.x >> 6, lane = threadIdx.x & 63;
  int m0 = blockIdx.x*128 + wv*32;
  int n0 = blockIdx.y*64;
  if(m0 >= M) return;
  int lr = lane & 15;
  int lk = (lane >> 4) << 3;
  f32x4 acc[2][4];
  #pragma unroll
  for(int a = 0; a < 2; ++a)
    #pragma unroll
    for(int b = 0; b < 4; ++b) acc[a][b] = (f32x4){0.f,0.f,0.f,0.f};
  const bf16x8 zero8 = {0,0,0,0,0,0,0,0};
  #pragma unroll
  for(int kc = 0; kc < HD; kc += 32){
    bf16x8 af[2], bf[4];
    #pragma unroll
    for(int mi = 0; mi < 2; ++mi){
      int r = m0 + mi*16 + lr;
      af[mi] = (r < M) ? *(const bf16x8*)&xb[(size_t)r*HD + kc + lk] : zero8;
    }
    #pragma unroll
    for(int ni = 0; ni < 4; ++ni){
      int c = n0 + ni*16 + lr;
      bf[ni] = *(const bf16x8*)&Wb[(size_t)c*HD + kc + lk];
    }
    #pragma unroll
    for(int mi = 0; mi < 2; ++mi)
      #pragma unroll
      for(int ni = 0; ni < 4; ++ni)
        acc[mi][ni] = __builtin_amdgcn_mfma_f32_16x16x32_bf16(af[mi], bf[ni], acc[mi][ni], 0, 0, 0);
  }
  float alpha = (MODE == 0) ? *alpha_p : 0.f;
  int rb = (lane >> 4) << 2;
  #pragma unroll
  for(int mi = 0; mi < 2; ++mi){
    #pragma unroll
    for(int j = 0; j < 4; ++j){
      int r = m0 + mi*16 + rb + j;
      if(r < M){
        float ra = rs_a[r];
        float inv = (MODE == 0) ? 1.f / rs_b[r] : 0.f;
        #pragma unroll
        for(int ni = 0; ni < 4; ++ni){
          int c = n0 + ni*16 + lr;
          float d = acc[mi][ni][j];
          if(MODE == 0){
            float v = (d + ra*cb[c]) * inv;
            v = prelu(v, alpha);
            out_f[(size_t)r*HD + c] = v;
            out_b[(size_t)r*HD + c] = f2bf(v);
          } else {
            float v = ra * (d + cb[c]);
            out_b[(size_t)r*HD + c] = f2bf(v);
          }
        }
      }
    }
  }
}

// ---------------------------------------------------------------------------
// Phase-2 aggregation from bf16 y + final epilogue. Depth-4 prefetch.
// ---------------------------------------------------------------------------
__global__ __launch_bounds__(256) void k_agg2(const unsigned short* __restrict__ yb,
        const int* __restrict__ offs, const int* __restrict__ csrc,
        const float* __restrict__ nrs, const float* __restrict__ alpha_p,
        float* __restrict__ out_nodes){
  int wv = threadIdx.x >> 6, lane = threadIdx.x & 63;
  int i = blockIdx.x*4 + wv;
  int b = offs[NHEDGE + i], cnt = offs[NHEDGE + i + 1] - b;
  const ushort4* tab = (const ushort4*)yb;
  float4 acc = make_float4(0.f,0.f,0.f,0.f);
  ushort4 v0={0,0,0,0}, v1={0,0,0,0}, v2={0,0,0,0}, v3={0,0,0,0};
  if(cnt > 0){ int j = csrc[b];   v0 = tab[(size_t)j*64 + lane]; }
  if(cnt > 1){ int j = csrc[b+1]; v1 = tab[(size_t)j*64 + lane]; }
  if(cnt > 2){ int j = csrc[b+2]; v2 = tab[(size_t)j*64 + lane]; }
  if(cnt > 3){ int j = csrc[b+3]; v3 = tab[(size_t)j*64 + lane]; }
  int k = 0;
  while(k < cnt){
    { ushort4 cv = v0;
      if(k + 4 < cnt){ int j = csrc[b+k+4]; v0 = tab[(size_t)j*64 + lane]; }
      acc.x += bf2f(cv.x); acc.y += bf2f(cv.y); acc.z += bf2f(cv.z); acc.w += bf2f(cv.w); }
    if(++k >= cnt) break;
    { ushort4 cv = v1;
      if(k + 4 < cnt){ int j = csrc[b+k+4]; v1 = tab[(size_t)j*64 + lane]; }
      acc.x += bf2f(cv.x); acc.y += bf2f(cv.y); acc.z += bf2f(cv.z); acc.w += bf2f(cv.w); }
    if(++k >= cnt) break;
    { ushort4 cv = v2;
      if(k + 4 < cnt){ int j = csrc[b+k+4]; v2 = tab[(size_t)j*64 + lane]; }
      acc.x += bf2f(cv.x); acc.y += bf2f(cv.y); acc.z += bf2f(cv.z); acc.w += bf2f(cv.w); }
    if(++k >= cnt) break;
    { ushort4 cv = v3;
      if(k + 4 < cnt){ int j = csrc[b+k+4]; v3 = tab[(size_t)j*64 + lane]; }
      acc.x += bf2f(cv.x); acc.y += bf2f(cv.y); acc.z += bf2f(cv.z); acc.w += bf2f(cv.w); }
    ++k;
  }
  float inv = 1.f / nrs[i];
  float a = *alpha_p;
  float4 o;
  o.x = prelu(acc.x*inv, a); o.y = prelu(acc.y*inv, a);
  o.z = prelu(acc.z*inv, a); o.w = prelu(acc.w*inv, a);
  *(float4*)&out_nodes[(size_t)i*HD + lane*4] = o;
}

// ---------------------------------------------------------------------------
extern "C" void kernel_launch(void* const* d_in, const int* in_sizes, int n_in,
                              void* d_out, int out_size, void* d_ws, size_t ws_size,
                              hipStream_t stream){
  const float* n_feat   = (const float*)d_in[0];
  const int*   node_idx  = (const int*)d_in[2];
  const int*   hedge_idx = (const int*)d_in[3];
  const float* nrw  = (const float*)d_in[4];
  const float* nrs  = (const float*)d_in[5];
  const float* hrw  = (const float*)d_in[6];
  const float* hrs  = (const float*)d_in[7];
  const float* W_in  = (const float*)d_in[8];
  const float* b_in  = (const float*)d_in[9];
  const float* W_n2e = (const float*)d_in[10];
  const float* b_n2e = (const float*)d_in[11];
  const float* W_e2n = (const float*)d_in[12];
  const float* b_e2n = (const float*)d_in[13];
  const float* alpha = (const float*)d_in[14];

  float* out_nodes = (float*)d_out;
  float* out_efeat = out_nodes + (size_t)NNODE * HD;

  // bf16 pre-scaled n_feat table lives in the out_nodes region of d_out: it is
  // consumed only by k_agg1, and k_agg2 (the last kernel) fully overwrites it.
  unsigned short* tabw = (unsigned short*)out_nodes;

  char* p = (char*)d_ws;
  auto take = [&](size_t bytes) -> void* {
    void* r = (void*)p;
    p += (bytes + 255) & ~(size_t)255;
    return r;
  };
  unsigned short* Wb0     = (unsigned short*)take((size_t)HD*HD*2);
  unsigned short* Wb1     = (unsigned short*)take((size_t)HD*HD*2);
  float*          bc      = (float*)take(HD*4);
  float*          aggw    = (float*)take(NHEDGE*4);
  unsigned short* aggx_b  = (unsigned short*)take((size_t)NHEDGE*HD*2);  // aliased as ybuf_b
  unsigned short* efeat_b = (unsigned short*)take((size_t)NHEDGE*HD*2);
  int*            offs    = (int*)take((NS+1)*4);
  int*            cnts    = (int*)take((size_t)NS*4);
  int*            pos     = (int*)take((size_t)NS*4);
  int*            bsum    = (int*)take(SCAN_B*4);
  int*            csrc    = (int*)take((size_t)2*NEDGE*4);
  unsigned short* ybuf_b  = aggx_b;  // safe alias: aggx dead after k_gemm<0>

  k_wprep<<<HD, 256, 0, stream>>>(W_in, b_in, W_n2e, b_n2e, W_e2n, Wb0, Wb1, bc, cnts);
  k_cvt<<<(NNODE*HD)/(256*8), 256, 0, stream>>>(n_feat, nrw, tabw);
  k_hist<<<(NEDGE+255)/256, 256, 0, stream>>>(node_idx, hedge_idx, cnts);
  k_scanA<<<SCAN_B, 256, 0, stream>>>(cnts, bsum);
  k_scanB<<<1, 64, 0, stream>>>(bsum);
  k_scanC<<<SCAN_B, 256, 0, stream>>>(cnts, bsum, offs, pos);
  k_fill<<<(NEDGE+255)/256, 256, 0, stream>>>(node_idx, hedge_idx, offs, pos, csrc);
  k_agg1<<<NHEDGE/4, 256, 0, stream>>>(tabw, nrw, offs, csrc, aggx_b, aggw);
  k_gemm<0><<<dim3((NHEDGE+127)/128, 4), 256, 0, stream>>>(aggx_b, Wb0, aggw, hrs, bc, alpha,
                                                           out_efeat, efeat_b, NHEDGE);
  k_gemm<1><<<dim3((NHEDGE+127)/128, 4), 256, 0, stream>>>(efeat_b, Wb1, hrw, nullptr, b_e2n, alpha,
                                                           nullptr, ybuf_b, NHEDGE);
  k_agg2<<<NNODE/4, 256, 0, stream>>>(ybuf_b, offs, csrc, nrs, alpha, out_nodes);
}